// Round 1
// baseline (765.552 us; speedup 1.0000x reference)
//
#include <hip/hip_runtime.h>
#include <math.h>

#define B_DIM 2
#define S_DIM 2048
#define E_DIM 768
#define H_DIM 8
#define D_DIM 96
#define M_DIM (B_DIM*S_DIM)          // 4096
#define SCALE_F 0.10206207261596575f // 96^-0.5

// ---------------------------------------------------------------------------
// GEMM + bias: out[M,768] = A[M,768] @ W[768,768] + bias
// BM=128, BN=64, BK=32; 256 threads; 8x4 register tile per thread.
// A staged transposed [k][m] in LDS so inner-loop reads are ds_read_b128.
// ---------------------------------------------------------------------------
__global__ __launch_bounds__(256) void gemm_bias_kernel(
    const float* __restrict__ A, const float* __restrict__ W,
    const float* __restrict__ bias, float* __restrict__ out)
{
    __shared__ float As[32][132];   // [k][m], pad 128->132 (float4-aligned stride)
    __shared__ float Ws[32][68];    // [k][n], pad 64->68

    const int tid = threadIdx.x;
    const int tx = tid & 15;        // col group: cols tx*4 .. tx*4+3
    const int ty = tid >> 4;        // row group: rows ty*8 .. ty*8+7
    const int row0 = blockIdx.y << 7;
    const int col0 = blockIdx.x << 6;

    float acc[8][4];
    #pragma unroll
    for (int i = 0; i < 8; ++i)
        #pragma unroll
        for (int j = 0; j < 4; ++j) acc[i][j] = 0.f;

    for (int k0 = 0; k0 < E_DIM; k0 += 32) {
        // stage A tile 128x32 (1024 float4, 4 per thread), transposed into LDS
        #pragma unroll
        for (int i = 0; i < 4; ++i) {
            int li = tid + (i << 8);
            int r  = li >> 3;             // 0..127
            int kv = (li & 7) << 2;       // 0..28
            float4 v = *(const float4*)(A + (size_t)(row0 + r)*E_DIM + k0 + kv);
            As[kv+0][r] = v.x; As[kv+1][r] = v.y;
            As[kv+2][r] = v.z; As[kv+3][r] = v.w;
        }
        // stage W tile 32x64 (512 float4, 2 per thread), row-major
        #pragma unroll
        for (int i = 0; i < 2; ++i) {
            int li = tid + (i << 8);
            int r  = li >> 4;             // 0..31
            int cv = (li & 15) << 2;      // 0..60
            float4 v = *(const float4*)(W + (size_t)(k0 + r)*E_DIM + col0 + cv);
            *(float4*)&Ws[r][cv] = v;
        }
        __syncthreads();

        #pragma unroll
        for (int kk = 0; kk < 32; ++kk) {
            float4 a0 = *(const float4*)&As[kk][(ty << 3)];
            float4 a1 = *(const float4*)&As[kk][(ty << 3) + 4];
            float4 bv = *(const float4*)&Ws[kk][(tx << 2)];
            float a[8] = {a0.x,a0.y,a0.z,a0.w,a1.x,a1.y,a1.z,a1.w};
            float bb[4] = {bv.x,bv.y,bv.z,bv.w};
            #pragma unroll
            for (int i = 0; i < 8; ++i)
                #pragma unroll
                for (int j = 0; j < 4; ++j)
                    acc[i][j] += a[i] * bb[j];
        }
        __syncthreads();
    }

    float4 b4 = *(const float4*)(bias + col0 + (tx << 2));
    #pragma unroll
    for (int i = 0; i < 8; ++i) {
        int row = row0 + (ty << 3) + i;
        float4 o;
        o.x = acc[i][0] + b4.x;
        o.y = acc[i][1] + b4.y;
        o.z = acc[i][2] + b4.z;
        o.w = acc[i][3] + b4.w;
        *(float4*)(out + (size_t)row*E_DIM + col0 + (tx << 2)) = o;
    }
}

// ---------------------------------------------------------------------------
// Flash-style attention, V == K (source bug), softmax scaling applied AFTER
// softmax (folded into final normalize).
// Block = (b, h, 64 q-rows). 256 threads: 8 threads per row-slot.
// Thread (jg = tid&7, r0 = tid>>3) owns rows {r0, r0+32}, cols {jg + 8u}.
// K tile staged transposed [d][j]; used for both QK^T and PV.
// ---------------------------------------------------------------------------
__global__ __launch_bounds__(256) void attn_kernel(
    const float* __restrict__ Q, const float* __restrict__ K,
    float* __restrict__ O)
{
    __shared__ float Qs[64][100];  // [row][d]
    __shared__ float Kt[96][68];   // [d][j]   (j within current key tile)
    __shared__ float Ps[64][68];   // [row][j] softmax probabilities

    const int tid = threadIdx.x;
    const int jg  = tid & 7;
    const int r0  = tid >> 3;      // 0..31
    const int b   = blockIdx.z;
    const int h   = blockIdx.y;
    const int q0  = blockIdx.x << 6;

    const float* Qbase = Q + ((size_t)(b*S_DIM + q0))*E_DIM + h*D_DIM;
    const float* Kbase = K + ((size_t)(b*S_DIM))*E_DIM + h*D_DIM;

    // load Q tile: 64 rows x 96
    for (int rep = 0; rep < 24; ++rep) {
        int i = (rep << 8) + tid;       // 0..6143
        int r = i / 96, d = i % 96;
        Qs[r][d] = Qbase[(size_t)r*E_DIM + d];
    }

    float m_i[2] = {-INFINITY, -INFINITY};
    float l_i[2] = {0.f, 0.f};
    float acc[2][12];
    #pragma unroll
    for (int rr = 0; rr < 2; ++rr)
        #pragma unroll
        for (int u = 0; u < 12; ++u) acc[rr][u] = 0.f;

    for (int kt = 0; kt < S_DIM/64; ++kt) {
        __syncthreads();   // previous iter's PV / Ps reads done
        // stage K tile 64x96 transposed -> Kt[d][j]
        const float* Kb = Kbase + ((size_t)(kt << 6))*E_DIM;
        for (int rep = 0; rep < 24; ++rep) {
            int i = (rep << 8) + tid;
            int j = i / 96, d = i % 96;
            Kt[d][j] = Kb[(size_t)j*E_DIM + d];
        }
        __syncthreads();

        // --- logits: rows {r0, r0+32}, keys j = jg*8 .. jg*8+7 ---
        float lg0[8], lg1[8];
        #pragma unroll
        for (int u = 0; u < 8; ++u) { lg0[u] = 0.f; lg1[u] = 0.f; }
        for (int d = 0; d < 96; ++d) {
            const float* krow = &Kt[d][jg << 3];
            float qa = Qs[r0][d];
            float qb = Qs[r0 + 32][d];
            #pragma unroll
            for (int u = 0; u < 8; ++u) {
                float kv = krow[u];
                lg0[u] += qa * kv;
                lg1[u] += qb * kv;
            }
        }

        // --- online softmax update (per row, replicated in the 8-lane group) ---
        #pragma unroll
        for (int rr = 0; rr < 2; ++rr) {
            float* lg = rr ? lg1 : lg0;
            float tmax = lg[0];
            #pragma unroll
            for (int u = 1; u < 8; ++u) tmax = fmaxf(tmax, lg[u]);
            tmax = fmaxf(tmax, __shfl_xor(tmax, 1, 8));
            tmax = fmaxf(tmax, __shfl_xor(tmax, 2, 8));
            tmax = fmaxf(tmax, __shfl_xor(tmax, 4, 8));

            float newm  = fmaxf(m_i[rr], tmax);
            float alpha = __expf(m_i[rr] - newm);
            m_i[rr] = newm;

            float p[8];
            float psum = 0.f;
            #pragma unroll
            for (int u = 0; u < 8; ++u) { p[u] = __expf(lg[u] - newm); psum += p[u]; }
            psum += __shfl_xor(psum, 1, 8);
            psum += __shfl_xor(psum, 2, 8);
            psum += __shfl_xor(psum, 4, 8);
            l_i[rr] = l_i[rr]*alpha + psum;

            #pragma unroll
            for (int u = 0; u < 12; ++u) acc[rr][u] *= alpha;

            int row = r0 + (rr << 5);
            #pragma unroll
            for (int u = 0; u < 8; ++u) Ps[row][(jg << 3) + u] = p[u];
        }
        __syncthreads();

        // --- PV: acc[rr][u] += sum_j Ps[row][j] * Kt[c][j], c = jg + 8u ---
        #pragma unroll 4
        for (int jb = 0; jb < 16; ++jb) {
            float4 p0 = *(const float4*)&Ps[r0][jb << 2];
            float4 p1 = *(const float4*)&Ps[r0 + 32][jb << 2];
            #pragma unroll
            for (int u = 0; u < 12; ++u) {
                int c = jg + (u << 3);
                float4 kv = *(const float4*)&Kt[c][jb << 2];
                acc[0][u] += p0.x*kv.x + p0.y*kv.y + p0.z*kv.z + p0.w*kv.w;
                acc[1][u] += p1.x*kv.x + p1.y*kv.y + p1.z*kv.z + p1.w*kv.w;
            }
        }
    }

    // --- finalize: /l, * SCALING (scaling applied after softmax per ref) ---
    float* Obase = O + ((size_t)(b*S_DIM + q0))*E_DIM + h*D_DIM;
    #pragma unroll
    for (int rr = 0; rr < 2; ++rr) {
        int row = r0 + (rr << 5);
        float inv = SCALE_F / l_i[rr];
        #pragma unroll
        for (int u = 0; u < 12; ++u)
            Obase[(size_t)row*E_DIM + jg + (u << 3)] = acc[rr][u] * inv;
    }
}

// ---------------------------------------------------------------------------
extern "C" void kernel_launch(void* const* d_in, const int* in_sizes, int n_in,
                              void* d_out, int out_size, void* d_ws, size_t ws_size,
                              hipStream_t stream)
{
    const float* x  = (const float*)d_in[0];
    const float* Wq = (const float*)d_in[1];
    const float* bq = (const float*)d_in[2];
    const float* Wk = (const float*)d_in[3];
    const float* bk = (const float*)d_in[4];
    const float* Wo = (const float*)d_in[5];
    const float* bo = (const float*)d_in[6];
    float* out = (float*)d_out;

    float* Qbuf  = (float*)d_ws;                       // [4096,768]
    float* Kbuf  = Qbuf  + (size_t)M_DIM * E_DIM;      // [4096,768] (also V)
    float* AObuf = Kbuf  + (size_t)M_DIM * E_DIM;      // [4096,768] attn context

    dim3 blk(256);
    dim3 ggrid(E_DIM/64, M_DIM/128);   // (12, 32)
    hipLaunchKernelGGL(gemm_bias_kernel, ggrid, blk, 0, stream, x, Wq, bq, Qbuf);
    hipLaunchKernelGGL(gemm_bias_kernel, ggrid, blk, 0, stream, x, Wk, bk, Kbuf);

    dim3 agrid(S_DIM/64, H_DIM, B_DIM); // (32, 8, 2)
    hipLaunchKernelGGL(attn_kernel, agrid, blk, 0, stream, Qbuf, Kbuf, AObuf);

    hipLaunchKernelGGL(gemm_bias_kernel, ggrid, blk, 0, stream, AObuf, Wo, bo, out);
}

// Round 2
// 398.250 us; speedup vs baseline: 1.9223x; 1.9223x over previous
//
#include <hip/hip_runtime.h>
#include <hip/hip_bf16.h>
#include <math.h>

#define B_DIM 2
#define S_DIM 2048
#define E_DIM 768
#define H_DIM 8
#define D_DIM 96
#define M_DIM (B_DIM*S_DIM)          // 4096
#define SCALE_F 0.10206207261596575f // 96^-0.5

typedef __bf16 bf16x8 __attribute__((ext_vector_type(8)));
typedef float  f32x4  __attribute__((ext_vector_type(4)));

#define MFMA16(a,b,c) __builtin_amdgcn_mfma_f32_16x16x32_bf16(a,b,c,0,0,0)

__device__ inline void split_bf16(float f, unsigned short& h, unsigned short& l) {
    __bf16 hb = (__bf16)f;                 // RNE
    float  r  = f - (float)hb;             // exact residual
    __bf16 lb = (__bf16)r;
    h = __builtin_bit_cast(unsigned short, hb);
    l = __builtin_bit_cast(unsigned short, lb);
}

// ---------------------------------------------------------------------------
// GEMM + bias: out[M,768] = A[M,768] @ W[768,768] + bias
// Optionally writes fp32 (outf) and/or split-bf16 hi/lo (outh/outl).
// ---------------------------------------------------------------------------
__global__ __launch_bounds__(256) void gemm_bias_kernel(
    const float* __restrict__ A, const float* __restrict__ W,
    const float* __restrict__ bias, float* __restrict__ outf,
    unsigned short* __restrict__ outh, unsigned short* __restrict__ outl)
{
    __shared__ float As[32][132];   // [k][m]
    __shared__ float Ws[32][68];    // [k][n]

    const int tid = threadIdx.x;
    const int tx = tid & 15;
    const int ty = tid >> 4;
    const int row0 = blockIdx.y << 7;
    const int col0 = blockIdx.x << 6;

    float acc[8][4];
    #pragma unroll
    for (int i = 0; i < 8; ++i)
        #pragma unroll
        for (int j = 0; j < 4; ++j) acc[i][j] = 0.f;

    for (int k0 = 0; k0 < E_DIM; k0 += 32) {
        #pragma unroll
        for (int i = 0; i < 4; ++i) {
            int li = tid + (i << 8);
            int r  = li >> 3;
            int kv = (li & 7) << 2;
            float4 v = *(const float4*)(A + (size_t)(row0 + r)*E_DIM + k0 + kv);
            As[kv+0][r] = v.x; As[kv+1][r] = v.y;
            As[kv+2][r] = v.z; As[kv+3][r] = v.w;
        }
        #pragma unroll
        for (int i = 0; i < 2; ++i) {
            int li = tid + (i << 8);
            int r  = li >> 4;
            int cv = (li & 15) << 2;
            float4 v = *(const float4*)(W + (size_t)(k0 + r)*E_DIM + col0 + cv);
            *(float4*)&Ws[r][cv] = v;
        }
        __syncthreads();

        #pragma unroll
        for (int kk = 0; kk < 32; ++kk) {
            float4 a0 = *(const float4*)&As[kk][(ty << 3)];
            float4 a1 = *(const float4*)&As[kk][(ty << 3) + 4];
            float4 bv = *(const float4*)&Ws[kk][(tx << 2)];
            float a[8] = {a0.x,a0.y,a0.z,a0.w,a1.x,a1.y,a1.z,a1.w};
            float bb[4] = {bv.x,bv.y,bv.z,bv.w};
            #pragma unroll
            for (int i = 0; i < 8; ++i)
                #pragma unroll
                for (int j = 0; j < 4; ++j)
                    acc[i][j] += a[i] * bb[j];
        }
        __syncthreads();
    }

    float4 b4 = *(const float4*)(bias + col0 + (tx << 2));
    #pragma unroll
    for (int i = 0; i < 8; ++i) {
        int row = row0 + (ty << 3) + i;
        float o[4];
        o[0] = acc[i][0] + b4.x; o[1] = acc[i][1] + b4.y;
        o[2] = acc[i][2] + b4.z; o[3] = acc[i][3] + b4.w;
        size_t off = (size_t)row*E_DIM + col0 + (tx << 2);
        if (outf) {
            float4 v; v.x=o[0]; v.y=o[1]; v.z=o[2]; v.w=o[3];
            *(float4*)(outf + off) = v;
        }
        if (outh) {
            ushort4 hh, ll;
            split_bf16(o[0], hh.x, ll.x);
            split_bf16(o[1], hh.y, ll.y);
            split_bf16(o[2], hh.z, ll.z);
            split_bf16(o[3], hh.w, ll.w);
            *(ushort4*)(outh + off) = hh;
            *(ushort4*)(outl + off) = ll;
        }
    }
}

// ---------------------------------------------------------------------------
// MFMA flash attention, V == K (source bug), scaling AFTER softmax.
// Block = (b, h, 64 q rows); 256 threads = 4 waves; wave w owns q rows
// [w*16, w*16+16).  Computes S^T per key-tile of 64:
//   S^T = Kh·Qh^T + Kh·Ql^T + Kl·Qh^T   (split-bf16 logits, fp32 accum)
// C-frag of S^T: col=lane&15 -> q (softmax state scalar per lane),
// row=quad*4+reg -> key.  P written b64-packed to Ps[q][key] which is the
// PV A-fragment layout.  PV B-frag from Kt[e][key] (V = K_hi transposed).
// ---------------------------------------------------------------------------
__global__ __launch_bounds__(256) void attn_mfma_kernel(
    const unsigned short* __restrict__ Qh, const unsigned short* __restrict__ Ql,
    const unsigned short* __restrict__ Kh, const unsigned short* __restrict__ Kl,
    float* __restrict__ O)
{
    __shared__ unsigned short sKh[64][104];  // [key][d]  (pad 96->104)
    __shared__ unsigned short sKl[64][104];
    __shared__ unsigned short sKt[96][72];   // [d(e)][key] (pad 64->72)
    __shared__ unsigned short sPs[64][72];   // [q][key]

    const int tid  = threadIdx.x;
    const int w    = tid >> 6;
    const int lane = tid & 63;
    const int qn   = lane & 15;   // n-index of fragments
    const int quad = lane >> 4;
    const int b    = blockIdx.z;
    const int h    = blockIdx.y;
    const int q0   = blockIdx.x << 6;

    // ---- Q fragments (B-operand: B[k=d][n=q], lane reads 8 contiguous d) ----
    bf16x8 qhf[3], qlf[3];
    {
        const size_t rowoff = ((size_t)(b*S_DIM + q0 + w*16 + qn))*E_DIM
                              + h*D_DIM + quad*8;
        #pragma unroll
        for (int kc = 0; kc < 3; ++kc) {
            qhf[kc] = *(const bf16x8*)(Qh + rowoff + kc*32);
            qlf[kc] = *(const bf16x8*)(Ql + rowoff + kc*32);
        }
    }

    f32x4 o[6];
    #pragma unroll
    for (int nt = 0; nt < 6; ++nt) { o[nt][0]=0.f; o[nt][1]=0.f; o[nt][2]=0.f; o[nt][3]=0.f; }
    float m_i = -INFINITY, l_i = 0.f;

    // staging assignment: 2 rows x 12 cols per thread
    const int j0 = (tid >> 3) << 1;      // 0..62
    const int dc = (tid & 7) * 12;       // 0..84

    for (int kt = 0; kt < S_DIM/64; ++kt) {
        __syncthreads();   // previous iteration's LDS reads complete

        // ---- stage K tile (bf16 hi/lo from global) ----
        {
            const size_t g0 = ((size_t)(b*S_DIM + (kt<<6) + j0))*E_DIM + h*D_DIM + dc;
            ushort4 h0[3], h1[3], l0[3], l1[3];
            #pragma unroll
            for (int i = 0; i < 3; ++i) {
                h0[i] = *(const ushort4*)(Kh + g0 + 4*i);
                h1[i] = *(const ushort4*)(Kh + g0 + E_DIM + 4*i);
                l0[i] = *(const ushort4*)(Kl + g0 + 4*i);
                l1[i] = *(const ushort4*)(Kl + g0 + E_DIM + 4*i);
            }
            #pragma unroll
            for (int i = 0; i < 3; ++i) {
                *(ushort4*)&sKh[j0  ][dc + 4*i] = h0[i];
                *(ushort4*)&sKh[j0+1][dc + 4*i] = h1[i];
                *(ushort4*)&sKl[j0  ][dc + 4*i] = l0[i];
                *(ushort4*)&sKl[j0+1][dc + 4*i] = l1[i];
            }
            const unsigned short* p0 = (const unsigned short*)h0;
            const unsigned short* p1 = (const unsigned short*)h1;
            #pragma unroll
            for (int c = 0; c < 12; ++c) {
                unsigned int pk = (unsigned int)p0[c] | ((unsigned int)p1[c] << 16);
                *(unsigned int*)&sKt[dc + c][j0] = pk;
            }
        }
        __syncthreads();   // staging visible

        // ---- S^T = K · Q^T (split-bf16) ----
        f32x4 s[4];
        #pragma unroll
        for (int mt = 0; mt < 4; ++mt) {
            f32x4 acc; acc[0]=0.f; acc[1]=0.f; acc[2]=0.f; acc[3]=0.f;
            #pragma unroll
            for (int kc = 0; kc < 3; ++kc) {
                bf16x8 ah = *(const bf16x8*)&sKh[mt*16 + qn][kc*32 + quad*8];
                bf16x8 al = *(const bf16x8*)&sKl[mt*16 + qn][kc*32 + quad*8];
                acc = MFMA16(ah, qhf[kc], acc);
                acc = MFMA16(ah, qlf[kc], acc);
                acc = MFMA16(al, qhf[kc], acc);
            }
            s[mt] = acc;
        }

        // ---- online softmax (per lane: q = qn; keys in 4 frags x 4 regs) ----
        float mx = s[0][0];
        #pragma unroll
        for (int mt = 0; mt < 4; ++mt)
            #pragma unroll
            for (int r = 0; r < 4; ++r) mx = fmaxf(mx, s[mt][r]);
        mx = fmaxf(mx, __shfl_xor(mx, 16));
        mx = fmaxf(mx, __shfl_xor(mx, 32));

        float m_new = fmaxf(m_i, mx);
        float alpha = __expf(m_i - m_new);
        m_i = m_new;

        float psum = 0.f;
        #pragma unroll
        for (int mt = 0; mt < 4; ++mt) {
            ushort4 pk;
            float p0 = __expf(s[mt][0] - m_new);
            float p1 = __expf(s[mt][1] - m_new);
            float p2 = __expf(s[mt][2] - m_new);
            float p3 = __expf(s[mt][3] - m_new);
            psum += p0 + p1 + p2 + p3;
            pk.x = __builtin_bit_cast(unsigned short, (__bf16)p0);
            pk.y = __builtin_bit_cast(unsigned short, (__bf16)p1);
            pk.z = __builtin_bit_cast(unsigned short, (__bf16)p2);
            pk.w = __builtin_bit_cast(unsigned short, (__bf16)p3);
            *(ushort4*)&sPs[w*16 + qn][mt*16 + quad*4] = pk;
        }
        psum += __shfl_xor(psum, 16);
        psum += __shfl_xor(psum, 32);
        l_i = l_i * alpha + psum;

        // rescale O accumulators: O rows are q_local = quad*4 + r, alpha lives
        // at lanes with (lane&15) == q_local -> broadcast from quad-0 lanes.
        #pragma unroll
        for (int r = 0; r < 4; ++r) {
            float ar = __shfl(alpha, ((lane >> 4) << 2) + r);
            #pragma unroll
            for (int nt = 0; nt < 6; ++nt) o[nt][r] *= ar;
        }

        // ---- PV: out[q][e] += P[q][key] · V[key][e] ----
        #pragma unroll
        for (int kc = 0; kc < 2; ++kc) {
            bf16x8 pa = *(const bf16x8*)&sPs[w*16 + qn][kc*32 + quad*8];
            #pragma unroll
            for (int nt = 0; nt < 6; ++nt) {
                bf16x8 vb = *(const bf16x8*)&sKt[nt*16 + qn][kc*32 + quad*8];
                o[nt] = MFMA16(pa, vb, o[nt]);
            }
        }
    }

    // ---- finalize: * SCALE / l (scaling after softmax per reference) ----
    #pragma unroll
    for (int r = 0; r < 4; ++r) {
        float li = __shfl(l_i, ((lane >> 4) << 2) + r);
        float sc = SCALE_F / li;
        float* po = O + ((size_t)(b*S_DIM + q0 + w*16 + (quad << 2) + r))*E_DIM
                      + h*D_DIM;
        #pragma unroll
        for (int nt = 0; nt < 6; ++nt)
            po[nt*16 + qn] = o[nt][r] * sc;
    }
}

// ---------------------------------------------------------------------------
extern "C" void kernel_launch(void* const* d_in, const int* in_sizes, int n_in,
                              void* d_out, int out_size, void* d_ws, size_t ws_size,
                              hipStream_t stream)
{
    const float* x  = (const float*)d_in[0];
    const float* Wq = (const float*)d_in[1];
    const float* bq = (const float*)d_in[2];
    const float* Wk = (const float*)d_in[3];
    const float* bk = (const float*)d_in[4];
    const float* Wo = (const float*)d_in[5];
    const float* bo = (const float*)d_in[6];
    float* out = (float*)d_out;

    const size_t NE = (size_t)M_DIM * E_DIM;
    float*          AObuf = (float*)d_ws;                 // fp32 context [4096,768]
    unsigned short* Qh = (unsigned short*)(AObuf + NE);
    unsigned short* Ql = Qh + NE;
    unsigned short* Kh = Ql + NE;
    unsigned short* Kl = Kh + NE;

    dim3 blk(256);
    dim3 ggrid(E_DIM/64, M_DIM/128);   // (12, 32)
    hipLaunchKernelGGL(gemm_bias_kernel, ggrid, blk, 0, stream, x, Wq, bq,
                       (float*)nullptr, Qh, Ql);
    hipLaunchKernelGGL(gemm_bias_kernel, ggrid, blk, 0, stream, x, Wk, bk,
                       (float*)nullptr, Kh, Kl);

    dim3 agrid(S_DIM/64, H_DIM, B_DIM); // (32, 8, 2)
    hipLaunchKernelGGL(attn_mfma_kernel, agrid, blk, 0, stream, Qh, Ql, Kh, Kl, AObuf);

    hipLaunchKernelGGL(gemm_bias_kernel, ggrid, blk, 0, stream, AObuf, Wo, bo,
                       out, (unsigned short*)nullptr, (unsigned short*)nullptr);
}

// Round 3
// 232.505 us; speedup vs baseline: 3.2926x; 1.7129x over previous
//
#include <hip/hip_runtime.h>
#include <hip/hip_bf16.h>
#include <math.h>
#include <stdint.h>

#define B_DIM 2
#define S_DIM 2048
#define E_DIM 768
#define H_DIM 8
#define D_DIM 96
#define M_DIM (B_DIM*S_DIM)          // 4096
#define SCALE_F 0.10206207261596575f // 96^-0.5

typedef __bf16 bf16x8 __attribute__((ext_vector_type(8)));
typedef float  f32x4  __attribute__((ext_vector_type(4)));

#define MFMA16(a,b,c) __builtin_amdgcn_mfma_f32_16x16x32_bf16(a,b,c,0,0,0)

__device__ inline void split_bf16(float f, unsigned short& h, unsigned short& l) {
    __bf16 hb = (__bf16)f;                 // RNE
    float  r  = f - (float)hb;             // exact residual
    __bf16 lb = (__bf16)r;
    h = __builtin_bit_cast(unsigned short, hb);
    l = __builtin_bit_cast(unsigned short, lb);
}

// CK-style async global->LDS, 16B per lane. LDS dest must be wave-uniform
// base + lane*16 (no padding in lane order).
__device__ inline void gload16(const void* g, void* l) {
    auto gp = reinterpret_cast<const __attribute__((address_space(1))) uint32_t*>(
        reinterpret_cast<uintptr_t>(g));
    auto lp = reinterpret_cast<__attribute__((address_space(3))) uint32_t*>(
        reinterpret_cast<uintptr_t>(l));
    __builtin_amdgcn_global_load_lds(gp, lp, 16, 0, 0);
}

// ---------------------------------------------------------------------------
// x [4096,768] fp32 -> split bf16 hi/lo
// ---------------------------------------------------------------------------
__global__ __launch_bounds__(256) void convert_x_kernel(
    const float* __restrict__ X, unsigned short* __restrict__ Xh,
    unsigned short* __restrict__ Xl)
{
    int i = (blockIdx.x * 256 + threadIdx.x) * 4;
    float4 v = *(const float4*)(X + i);
    ushort4 h, l;
    split_bf16(v.x, h.x, l.x);
    split_bf16(v.y, h.y, l.y);
    split_bf16(v.z, h.z, l.z);
    split_bf16(v.w, h.w, l.w);
    *(ushort4*)(Xh + i) = h;
    *(ushort4*)(Xl + i) = l;
}

// ---------------------------------------------------------------------------
// W [768,768] fp32 [k][n] -> W^T bf16 [n][k] (hi, optional lo), 64x64 tiles
// ---------------------------------------------------------------------------
__global__ __launch_bounds__(256) void convert_wT_kernel(
    const float* __restrict__ W, unsigned short* __restrict__ Th,
    unsigned short* __restrict__ Tl)
{
    __shared__ float tile[64][65];
    const int tid = threadIdx.x;
    const int k0 = blockIdx.y << 6, n0 = blockIdx.x << 6;
    const int r = tid >> 4, c4 = (tid & 15) << 2;
    #pragma unroll
    for (int i = 0; i < 4; ++i) {
        float4 v = *(const float4*)(W + (size_t)(k0 + r + i*16)*E_DIM + n0 + c4);
        tile[r + i*16][c4+0] = v.x; tile[r + i*16][c4+1] = v.y;
        tile[r + i*16][c4+2] = v.z; tile[r + i*16][c4+3] = v.w;
    }
    __syncthreads();
    #pragma unroll
    for (int i = 0; i < 4; ++i) {
        int n = r + i*16;
        ushort4 h, l;
        split_bf16(tile[c4+0][n], h.x, l.x);
        split_bf16(tile[c4+1][n], h.y, l.y);
        split_bf16(tile[c4+2][n], h.z, l.z);
        split_bf16(tile[c4+3][n], h.w, l.w);
        *(ushort4*)(Th + (size_t)(n0 + n)*E_DIM + k0 + c4) = h;
        if (Tl) *(ushort4*)(Tl + (size_t)(n0 + n)*E_DIM + k0 + c4) = l;
    }
}

// ---------------------------------------------------------------------------
// Fused Q/K projection, split-bf16 precision:
//   C[m,n] = Ah·Bh + Ah·Bl + Al·Bh   (A = x, B^T = [Wq|Wk] pre-transposed)
// 128x128 tile, BK=32, 256 thr = 4 waves (2x2 of 64x64), m97-style
// global_load_lds staging, unpadded LDS. Epilogue: +bias, split-bf16 out.
// ---------------------------------------------------------------------------
__global__ __launch_bounds__(256) void gemm_qk_kernel(
    const unsigned short* __restrict__ Ah, const unsigned short* __restrict__ Al,
    const unsigned short* __restrict__ Bh, const unsigned short* __restrict__ Bl,
    const float* __restrict__ bq, const float* __restrict__ bk,
    unsigned short* __restrict__ Qh, unsigned short* __restrict__ Ql,
    unsigned short* __restrict__ Kh, unsigned short* __restrict__ Kl)
{
    __shared__ unsigned short sAh[128*32], sAl[128*32];
    __shared__ unsigned short sBh[128*32], sBl[128*32];

    const int tid  = threadIdx.x;
    const int lane = tid & 63;
    const int w    = tid >> 6;
    const int qn   = lane & 15, quad = lane >> 4;
    const int wm   = w & 1, wn = w >> 1;
    const int row0 = blockIdx.y << 7;
    const int col0 = blockIdx.x << 7;   // 0..1408 (Q: <768, K: >=768)

    const int sr = tid >> 2;            // 0..63
    const int sk = (tid & 3) << 3;      // 0,8,16,24

    const unsigned short* gAh = Ah + (size_t)(row0 + sr)*E_DIM + sk;
    const unsigned short* gAl = Al + (size_t)(row0 + sr)*E_DIM + sk;
    const unsigned short* gBh = Bh + (size_t)(col0 + sr)*E_DIM + sk;
    const unsigned short* gBl = Bl + (size_t)(col0 + sr)*E_DIM + sk;

    f32x4 acc[4][4];
    #pragma unroll
    for (int mt = 0; mt < 4; ++mt)
        #pragma unroll
        for (int nt = 0; nt < 4; ++nt)
            { acc[mt][nt][0]=0.f; acc[mt][nt][1]=0.f; acc[mt][nt][2]=0.f; acc[mt][nt][3]=0.f; }

    for (int k0 = 0; k0 < E_DIM; k0 += 32) {
        __syncthreads();
        gload16(gAh + k0,              sAh + tid*8);
        gload16(gAh + 64*E_DIM + k0,   sAh + 2048 + tid*8);
        gload16(gAl + k0,              sAl + tid*8);
        gload16(gAl + 64*E_DIM + k0,   sAl + 2048 + tid*8);
        gload16(gBh + k0,              sBh + tid*8);
        gload16(gBh + 64*E_DIM + k0,   sBh + 2048 + tid*8);
        gload16(gBl + k0,              sBl + tid*8);
        gload16(gBl + 64*E_DIM + k0,   sBl + 2048 + tid*8);
        __syncthreads();

        bf16x8 afh[4], afl[4], bfh[4], bfl[4];
        #pragma unroll
        for (int mt = 0; mt < 4; ++mt) {
            int m = wm*64 + mt*16 + qn;
            afh[mt] = *(const bf16x8*)&sAh[m*32 + quad*8];
            afl[mt] = *(const bf16x8*)&sAl[m*32 + quad*8];
        }
        #pragma unroll
        for (int nt = 0; nt < 4; ++nt) {
            int n = wn*64 + nt*16 + qn;
            bfh[nt] = *(const bf16x8*)&sBh[n*32 + quad*8];
            bfl[nt] = *(const bf16x8*)&sBl[n*32 + quad*8];
        }
        #pragma unroll
        for (int mt = 0; mt < 4; ++mt)
            #pragma unroll
            for (int nt = 0; nt < 4; ++nt) {
                acc[mt][nt] = MFMA16(afh[mt], bfh[nt], acc[mt][nt]);
                acc[mt][nt] = MFMA16(afh[mt], bfl[nt], acc[mt][nt]);
                acc[mt][nt] = MFMA16(afl[mt], bfh[nt], acc[mt][nt]);
            }
    }

    #pragma unroll
    for (int nt = 0; nt < 4; ++nt) {
        int n = col0 + wn*64 + nt*16 + qn;
        bool isQ = n < E_DIM;
        float bias = isQ ? bq[n] : bk[n - E_DIM];
        unsigned short* oh = isQ ? Qh : Kh;
        unsigned short* ol = isQ ? Ql : Kl;
        int nc = isQ ? n : n - E_DIM;
        #pragma unroll
        for (int mt = 0; mt < 4; ++mt)
            #pragma unroll
            for (int r = 0; r < 4; ++r) {
                int m = row0 + wm*64 + mt*16 + quad*4 + r;
                unsigned short hh, ll;
                split_bf16(acc[mt][nt][r] + bias, hh, ll);
                oh[(size_t)m*E_DIM + nc] = hh;
                ol[(size_t)m*E_DIM + nc] = ll;
            }
    }
}

// ---------------------------------------------------------------------------
// Output projection, plain bf16: out[m,n] = AO·Wo^T + bo (fp32 out)
// ---------------------------------------------------------------------------
__global__ __launch_bounds__(256) void gemm_out_kernel(
    const unsigned short* __restrict__ A, const unsigned short* __restrict__ Bt,
    const float* __restrict__ bo, float* __restrict__ out)
{
    __shared__ unsigned short sA[128*32];
    __shared__ unsigned short sB[128*32];

    const int tid  = threadIdx.x;
    const int lane = tid & 63;
    const int w    = tid >> 6;
    const int qn   = lane & 15, quad = lane >> 4;
    const int wm   = w & 1, wn = w >> 1;
    const int row0 = blockIdx.y << 7;
    const int col0 = blockIdx.x << 7;

    const int sr = tid >> 2;
    const int sk = (tid & 3) << 3;

    const unsigned short* gA = A  + (size_t)(row0 + sr)*E_DIM + sk;
    const unsigned short* gB = Bt + (size_t)(col0 + sr)*E_DIM + sk;

    f32x4 acc[4][4];
    #pragma unroll
    for (int mt = 0; mt < 4; ++mt)
        #pragma unroll
        for (int nt = 0; nt < 4; ++nt)
            { acc[mt][nt][0]=0.f; acc[mt][nt][1]=0.f; acc[mt][nt][2]=0.f; acc[mt][nt][3]=0.f; }

    for (int k0 = 0; k0 < E_DIM; k0 += 32) {
        __syncthreads();
        gload16(gA + k0,            sA + tid*8);
        gload16(gA + 64*E_DIM + k0, sA + 2048 + tid*8);
        gload16(gB + k0,            sB + tid*8);
        gload16(gB + 64*E_DIM + k0, sB + 2048 + tid*8);
        __syncthreads();

        bf16x8 af[4], bf[4];
        #pragma unroll
        for (int mt = 0; mt < 4; ++mt)
            af[mt] = *(const bf16x8*)&sA[(wm*64 + mt*16 + qn)*32 + quad*8];
        #pragma unroll
        for (int nt = 0; nt < 4; ++nt)
            bf[nt] = *(const bf16x8*)&sB[(wn*64 + nt*16 + qn)*32 + quad*8];
        #pragma unroll
        for (int mt = 0; mt < 4; ++mt)
            #pragma unroll
            for (int nt = 0; nt < 4; ++nt)
                acc[mt][nt] = MFMA16(af[mt], bf[nt], acc[mt][nt]);
    }

    #pragma unroll
    for (int nt = 0; nt < 4; ++nt) {
        int n = col0 + wn*64 + nt*16 + qn;
        float bias = bo[n];
        #pragma unroll
        for (int mt = 0; mt < 4; ++mt)
            #pragma unroll
            for (int r = 0; r < 4; ++r) {
                int m = row0 + wm*64 + mt*16 + quad*4 + r;
                out[(size_t)m*E_DIM + n] = acc[mt][nt][r] + bias;
            }
    }
}

// ---------------------------------------------------------------------------
// MFMA flash attention (unchanged from R1 except bf16 output).
// ---------------------------------------------------------------------------
__global__ __launch_bounds__(256) void attn_mfma_kernel(
    const unsigned short* __restrict__ Qh, const unsigned short* __restrict__ Ql,
    const unsigned short* __restrict__ Kh, const unsigned short* __restrict__ Kl,
    unsigned short* __restrict__ O)
{
    __shared__ unsigned short sKh[64][104];
    __shared__ unsigned short sKl[64][104];
    __shared__ unsigned short sKt[96][72];
    __shared__ unsigned short sPs[64][72];

    const int tid  = threadIdx.x;
    const int w    = tid >> 6;
    const int lane = tid & 63;
    const int qn   = lane & 15;
    const int quad = lane >> 4;
    const int b    = blockIdx.z;
    const int h    = blockIdx.y;
    const int q0   = blockIdx.x << 6;

    bf16x8 qhf[3], qlf[3];
    {
        const size_t rowoff = ((size_t)(b*S_DIM + q0 + w*16 + qn))*E_DIM
                              + h*D_DIM + quad*8;
        #pragma unroll
        for (int kc = 0; kc < 3; ++kc) {
            qhf[kc] = *(const bf16x8*)(Qh + rowoff + kc*32);
            qlf[kc] = *(const bf16x8*)(Ql + rowoff + kc*32);
        }
    }

    f32x4 o[6];
    #pragma unroll
    for (int nt = 0; nt < 6; ++nt) { o[nt][0]=0.f; o[nt][1]=0.f; o[nt][2]=0.f; o[nt][3]=0.f; }
    float m_i = -INFINITY, l_i = 0.f;

    const int j0 = (tid >> 3) << 1;
    const int dc = (tid & 7) * 12;

    for (int kt = 0; kt < S_DIM/64; ++kt) {
        __syncthreads();
        {
            const size_t g0 = ((size_t)(b*S_DIM + (kt<<6) + j0))*E_DIM + h*D_DIM + dc;
            ushort4 h0[3], h1[3], l0[3], l1[3];
            #pragma unroll
            for (int i = 0; i < 3; ++i) {
                h0[i] = *(const ushort4*)(Kh + g0 + 4*i);
                h1[i] = *(const ushort4*)(Kh + g0 + E_DIM + 4*i);
                l0[i] = *(const ushort4*)(Kl + g0 + 4*i);
                l1[i] = *(const ushort4*)(Kl + g0 + E_DIM + 4*i);
            }
            #pragma unroll
            for (int i = 0; i < 3; ++i) {
                *(ushort4*)&sKh[j0  ][dc + 4*i] = h0[i];
                *(ushort4*)&sKh[j0+1][dc + 4*i] = h1[i];
                *(ushort4*)&sKl[j0  ][dc + 4*i] = l0[i];
                *(ushort4*)&sKl[j0+1][dc + 4*i] = l1[i];
            }
            const unsigned short* p0 = (const unsigned short*)h0;
            const unsigned short* p1 = (const unsigned short*)h1;
            #pragma unroll
            for (int c = 0; c < 12; ++c) {
                unsigned int pk = (unsigned int)p0[c] | ((unsigned int)p1[c] << 16);
                *(unsigned int*)&sKt[dc + c][j0] = pk;
            }
        }
        __syncthreads();

        f32x4 s[4];
        #pragma unroll
        for (int mt = 0; mt < 4; ++mt) {
            f32x4 acc; acc[0]=0.f; acc[1]=0.f; acc[2]=0.f; acc[3]=0.f;
            #pragma unroll
            for (int kc = 0; kc < 3; ++kc) {
                bf16x8 ah = *(const bf16x8*)&sKh[mt*16 + qn][kc*32 + quad*8];
                bf16x8 al = *(const bf16x8*)&sKl[mt*16 + qn][kc*32 + quad*8];
                acc = MFMA16(ah, qhf[kc], acc);
                acc = MFMA16(ah, qlf[kc], acc);
                acc = MFMA16(al, qhf[kc], acc);
            }
            s[mt] = acc;
        }

        float mx = s[0][0];
        #pragma unroll
        for (int mt = 0; mt < 4; ++mt)
            #pragma unroll
            for (int r = 0; r < 4; ++r) mx = fmaxf(mx, s[mt][r]);
        mx = fmaxf(mx, __shfl_xor(mx, 16));
        mx = fmaxf(mx, __shfl_xor(mx, 32));

        float m_new = fmaxf(m_i, mx);
        float alpha = __expf(m_i - m_new);
        m_i = m_new;

        float psum = 0.f;
        #pragma unroll
        for (int mt = 0; mt < 4; ++mt) {
            ushort4 pk;
            float p0 = __expf(s[mt][0] - m_new);
            float p1 = __expf(s[mt][1] - m_new);
            float p2 = __expf(s[mt][2] - m_new);
            float p3 = __expf(s[mt][3] - m_new);
            psum += p0 + p1 + p2 + p3;
            pk.x = __builtin_bit_cast(unsigned short, (__bf16)p0);
            pk.y = __builtin_bit_cast(unsigned short, (__bf16)p1);
            pk.z = __builtin_bit_cast(unsigned short, (__bf16)p2);
            pk.w = __builtin_bit_cast(unsigned short, (__bf16)p3);
            *(ushort4*)&sPs[w*16 + qn][mt*16 + quad*4] = pk;
        }
        psum += __shfl_xor(psum, 16);
        psum += __shfl_xor(psum, 32);
        l_i = l_i * alpha + psum;

        #pragma unroll
        for (int r = 0; r < 4; ++r) {
            float ar = __shfl(alpha, ((lane >> 4) << 2) + r);
            #pragma unroll
            for (int nt = 0; nt < 6; ++nt) o[nt][r] *= ar;
        }

        #pragma unroll
        for (int kc = 0; kc < 2; ++kc) {
            bf16x8 pa = *(const bf16x8*)&sPs[w*16 + qn][kc*32 + quad*8];
            #pragma unroll
            for (int nt = 0; nt < 6; ++nt) {
                bf16x8 vb = *(const bf16x8*)&sKt[nt*16 + qn][kc*32 + quad*8];
                o[nt] = MFMA16(pa, vb, o[nt]);
            }
        }
    }

    #pragma unroll
    for (int r = 0; r < 4; ++r) {
        float li = __shfl(l_i, ((lane >> 4) << 2) + r);
        float sc = SCALE_F / li;
        unsigned short* po = O + ((size_t)(b*S_DIM + q0 + w*16 + (quad << 2) + r))*E_DIM
                               + h*D_DIM;
        #pragma unroll
        for (int nt = 0; nt < 6; ++nt)
            po[nt*16 + qn] = __builtin_bit_cast(unsigned short, (__bf16)(o[nt][r] * sc));
    }
}

// ---------------------------------------------------------------------------
extern "C" void kernel_launch(void* const* d_in, const int* in_sizes, int n_in,
                              void* d_out, int out_size, void* d_ws, size_t ws_size,
                              hipStream_t stream)
{
    const float* x  = (const float*)d_in[0];
    const float* Wq = (const float*)d_in[1];
    const float* bq = (const float*)d_in[2];
    const float* Wk = (const float*)d_in[3];
    const float* bk = (const float*)d_in[4];
    const float* Wo = (const float*)d_in[5];
    const float* bo = (const float*)d_in[6];
    float* out = (float*)d_out;

    const size_t NE = (size_t)M_DIM * E_DIM;        // 3.1M
    const size_t WE = (size_t)E_DIM * E_DIM;        // 590K
    unsigned short* xh    = (unsigned short*)d_ws;  // NE (aliased as AObf later)
    unsigned short* xl    = xh + NE;
    unsigned short* WqkTh = xl + NE;                // 2*WE
    unsigned short* WqkTl = WqkTh + 2*WE;           // 2*WE
    unsigned short* WoTh  = WqkTl + 2*WE;           // WE
    unsigned short* Qh    = WoTh + WE;
    unsigned short* Ql    = Qh + NE;
    unsigned short* Kh    = Ql + NE;
    unsigned short* Kl    = Kh + NE;
    unsigned short* AObf  = xh;                     // alias: xh dead after gemm_qk

    dim3 blk(256);
    hipLaunchKernelGGL(convert_x_kernel, dim3(NE/1024), blk, 0, stream, x, xh, xl);
    hipLaunchKernelGGL(convert_wT_kernel, dim3(12,12), blk, 0, stream, Wq, WqkTh, WqkTl);
    hipLaunchKernelGGL(convert_wT_kernel, dim3(12,12), blk, 0, stream, Wk, WqkTh + WE, WqkTl + WE);
    hipLaunchKernelGGL(convert_wT_kernel, dim3(12,12), blk, 0, stream, Wo, WoTh, (unsigned short*)nullptr);

    hipLaunchKernelGGL(gemm_qk_kernel, dim3(12,32), blk, 0, stream,
                       xh, xl, WqkTh, WqkTl, bq, bk, Qh, Ql, Kh, Kl);

    hipLaunchKernelGGL(attn_mfma_kernel, dim3(S_DIM/64, H_DIM, B_DIM), blk, 0, stream,
                       Qh, Ql, Kh, Kl, AObf);

    hipLaunchKernelGGL(gemm_out_kernel, dim3(6,32), blk, 0, stream,
                       AObf, WoTh, bo, out);
}